// Round 2
// baseline (880.367 us; speedup 1.0000x reference)
//
#include <hip/hip_runtime.h>
#include <stdint.h>

#define NN    6000
#define KNNC  10
#define MM    (NN * 2 * (KNNC + 1))   // 132000
#define DD    (2 * NN)                // 12000
#define LCH   3                       // hidden layers (LC-1)
#define BLK   256

// One MLP wave (64 rows) per block -> ceil(132000/64) = 2063 blocks.
#define FBLOCKS ((MM + 63) / 64)      // 2063
#define NV      ((long long)DD * DD / 4)   // 36,000,000 float4s

// Wave-specialized fused kernel: 3 waves stream float4 zeros into the 576MB
// output, 1 wave computes 64 MLP rows (one per lane).
//
// Round-1 fix: the k-loop previously re-read the 48KB Whid from global per
// wave (3072 dwordx4 loads) -> those loads queued behind the saturated fill
// store stream (VMEM contention) and/or compiled to s_load, whose lgkmcnt
// aliases the activation ds_reads -> coarse waits serialized every FMA
// batch. Whid is now staged into LDS ONCE per block by the MLP wave itself
// (same-wave DS ordering: no barrier), and the hot loop is pure
// wave-uniform ds_read_b128 (broadcast, conflict-free) + FMA. Zero VMEM in
// the inner loop. LDS = 48KB weights + 16KB activations = 64KB -> 2
// blocks/CU; 6 fill waves/CU still saturate store BW (harness fill hits
// 6.15 TB/s at 3.3 waves/CU).
__global__ __launch_bounds__(BLK) void fused_mlp_zero(
    const float* __restrict__ CK,    // [MM,3]
    const float* __restrict__ Win,   // [3,64]
    const float* __restrict__ bin,   // [64]
    const float* __restrict__ Whid,  // [3,64,64]
    const float* __restrict__ bhid,  // [3,64]
    const float* __restrict__ Wout,  // [64,4]
    const float* __restrict__ bout,  // [4]
    float* __restrict__ vals,        // [MM,2] (workspace)
    float* __restrict__ out)         // [DD*DD], zero-filled here
{
    __shared__ float4 sW4[3 * 64 * 16];  // Whid staged, 48 KiB
    __shared__ float  sH[64 * 64];       // activations [k][lane], 16 KiB

    const int tid  = threadIdx.x;
    const int wave = tid >> 6;
    const int lane = tid & 63;
    const int mlpw = blockIdx.x & 3;          // rotate MLP wave slot across SIMDs

    if (wave != mlpw) {
        // ---- fill specialization: 3 waves per block ----
        const int fw = wave - (wave > mlpw ? 1 : 0);       // 0..2
        const long long ft = (long long)blockIdx.x * 192 + fw * 64 + lane;
        const long long stride = (long long)FBLOCKS * 192;
        float4 z = make_float4(0.f, 0.f, 0.f, 0.f);
        float4* outv = (float4*)out;
        for (long long i = ft; i < NV; i += stride) outv[i] = z;
        return;
    }

    // ---- MLP specialization ----
    // Stage all hidden weights to LDS (one time, ~48 global dwordx4/lane).
    // Only this wave touches sW4/sH -> in-order DS pipe, no barrier needed.
    {
        const float4* __restrict__ Wg = (const float4*)Whid;
#pragma unroll 4
        for (int i = lane; i < 3 * 64 * 16; i += 64) sW4[i] = Wg[i];
    }

    const int m0 = blockIdx.x * 64 + lane;
    const int m  = m0 < MM ? m0 : MM - 1;     // clamp: loads safe, store guarded

    const float x0 = CK[m * 3 + 0];
    const float x1 = CK[m * 3 + 1];
    const float x2 = CK[m * 3 + 2];

    float* __restrict__ hcol = sH + lane;     // h[k] lives at hcol[k*64]

    // Input layer 3 -> 64; weight/bias reads wave-uniform (s_load, one-time).
#pragma unroll
    for (int j = 0; j < 64; j++) {
        float a = bin[j];
        a = fmaf(x0, Win[j],       a);
        a = fmaf(x1, Win[64 + j],  a);
        a = fmaf(x2, Win[128 + j], a);
        hcol[j * 64] = fmaxf(a, 0.0f);        // static addr: ds_write_b32
    }

    // Hidden layers: g_j = sum_k W[k][j] * h_k. Pure LDS + VALU hot loop.
#pragma unroll 1
    for (int l = 0; l < LCH; l++) {
        const float*  __restrict__ bh  = bhid + (l << 6);
        const float4* __restrict__ Wl4 = sW4 + (l << 10);   // 64 rows x 16 float4
        float g[64];
#pragma unroll
        for (int j = 0; j < 64; j++) g[j] = bh[j];
#pragma unroll 8
        for (int k = 0; k < 64; k++) {
            const float hk = hcol[k * 64];    // ds_read_b32 (2-way alias: free)
            const float4* __restrict__ Wk = Wl4 + (k << 4);
#pragma unroll
            for (int j4 = 0; j4 < 16; j4++) {
                float4 w = Wk[j4];            // uniform ds_read_b128 broadcast
                g[j4 * 4 + 0] = fmaf(w.x, hk, g[j4 * 4 + 0]);
                g[j4 * 4 + 1] = fmaf(w.y, hk, g[j4 * 4 + 1]);
                g[j4 * 4 + 2] = fmaf(w.z, hk, g[j4 * 4 + 2]);
                g[j4 * 4 + 3] = fmaf(w.w, hk, g[j4 * 4 + 3]);
            }
        }
#pragma unroll
        for (int j = 0; j < 64; j++) hcol[j * 64] = fmaxf(g[j], 0.0f);
    }

    // Output layer collapsed over mi: vals[:,mj] = C[:,mj] + C[:,mj+2]
    float v0 = bout[0] + bout[2];
    float v1 = bout[1] + bout[3];
#pragma unroll 8
    for (int k = 0; k < 64; k++) {
        float4 wo = *((const float4*)Wout + k);
        const float hk = hcol[k * 64];
        v0 = fmaf(hk, wo.x + wo.z, v0);
        v1 = fmaf(hk, wo.y + wo.w, v1);
    }
    if (m0 < MM) *(float2*)(vals + 2 * m0) = make_float2(v0, v1);
}

__global__ __launch_bounds__(BLK) void scatter_add(
    const float* __restrict__ vals,   // [MM,2]
    const int* __restrict__ coo,      // [2,MM]
    float* __restrict__ out)          // [DD*DD]
{
    const int t = blockIdx.x * BLK + threadIdx.x;
    if (t >= MM) return;
    const int r2 = coo[t] * 2;        // row index * MODES
    const int c2 = coo[MM + t] * 2;   // col index * MODES
    const float2 v = *(const float2*)(vals + 2 * t);
    // mj=0: element (r2, c2); mj=1: element (r2+1, c2+1) = +DD+1 flat
    const long long f0 = (long long)r2 * DD + c2;
    atomicAdd(out + f0, v.x);
    atomicAdd(out + f0 + DD + 1, v.y);
}

extern "C" void kernel_launch(void* const* d_in, const int* in_sizes, int n_in,
                              void* d_out, int out_size, void* d_ws, size_t ws_size,
                              hipStream_t stream) {
    const float* CK   = (const float*)d_in[0];
    const float* Win  = (const float*)d_in[1];
    const float* bin  = (const float*)d_in[2];
    const float* Whid = (const float*)d_in[3];
    const float* bhid = (const float*)d_in[4];
    const float* Wout = (const float*)d_in[5];
    const float* bout = (const float*)d_in[6];
    const int* coo    = (const int*)d_in[7];
    float* out        = (float*)d_out;
    float* vals       = (float*)d_ws;

    fused_mlp_zero<<<FBLOCKS, BLK, 0, stream>>>(
        CK, Win, bin, Whid, bhid, Wout, bout, vals, out);
    scatter_add<<<(MM + BLK - 1) / BLK, BLK, 0, stream>>>(vals, coo, out);
}

// Round 3
// 717.699 us; speedup vs baseline: 1.2267x; 1.2267x over previous
//
#include <hip/hip_runtime.h>
#include <stdint.h>

#define NN    6000
#define KNNC  10
#define MM    (NN * 2 * (KNNC + 1))   // 132000
#define DD    (2 * NN)                // 12000
#define LCH   3                       // hidden layers (LC-1)
#define BLK   256

// Block-specialized grid: every 5th block is an MLP block (4 waves x 64 rows
// = 256 rows), the rest are pure zero-fill blocks. 516 MLP blocks cover all
// 132000 rows; 2064 fill blocks stream the 576MB output.
//
// Round-2 post-mortem: WAVE-specialization coupled fill and MLP in one
// workgroup -> each block round ended with a long MLP-only tail during which
// the CU issued no stores (measured: 4.8% occupancy, 1.5 TB/s write BW, 19%
// of peak). BLOCK-specialization decouples them: fill blocks drain and are
// backfilled by the scheduler while MLP blocks run concurrently elsewhere.
// LDS weight staging also regressed (R2) -> weights stay wave-uniform global
// float4 reads (s_load path, 48KB L2-hot). Activations stay in LDS [k][tid]
// (2 lanes/bank alias = free, per m136) so no register array is ever
// dynamically indexed (no scratch).
#define NMLPB  516
#define NFILLB 2064
#define GRID   (NMLPB + NFILLB)            // 2580
#define NV     ((long long)DD * DD / 4)    // 36,000,000 float4s

__global__ __launch_bounds__(BLK) void fill_mlp(
    const float* __restrict__ CK,    // [MM,3]
    const float* __restrict__ Win,   // [3,64]
    const float* __restrict__ bin,   // [64]
    const float* __restrict__ Whid,  // [3,64,64]
    const float* __restrict__ bhid,  // [3,64]
    const float* __restrict__ Wout,  // [64,4]
    const float* __restrict__ bout,  // [4]
    float* __restrict__ vals,        // [MM,2] (workspace)
    float* __restrict__ out)         // [DD*DD], zero-filled here
{
    __shared__ float sH[64 * BLK];   // activations [k][tid], 64 KiB

    const int bid = blockIdx.x;
    const int tid = threadIdx.x;
    const int p   = bid % 5;

    if (p != 2) {
        // ---- fill block: stream float4 zeros ----
        const int fid = (bid / 5) * 4 + p - (p > 2 ? 1 : 0);   // 0..2063
        long long i = (long long)fid * BLK + tid;
        const long long stride = (long long)NFILLB * BLK;      // 528384
        float4 z = make_float4(0.f, 0.f, 0.f, 0.f);
        float4* outv = (float4*)out;
        for (; i < NV; i += stride) outv[i] = z;
        return;
    }

    // ---- MLP block: 256 rows, one per thread ----
    const int m0 = (bid / 5) * BLK + tid;      // 0..132095
    const int m  = m0 < MM ? m0 : MM - 1;      // clamp loads, guard store

    const float x0 = CK[m * 3 + 0];
    const float x1 = CK[m * 3 + 1];
    const float x2 = CK[m * 3 + 2];

    float* __restrict__ hcol = sH + tid;       // h[k] lives at hcol[k*256]

    // Input layer 3 -> 64; weight/bias reads wave-uniform (broadcast).
#pragma unroll
    for (int j = 0; j < 64; j++) {
        float a = bin[j];
        a = fmaf(x0, Win[j],       a);
        a = fmaf(x1, Win[64 + j],  a);
        a = fmaf(x2, Win[128 + j], a);
        hcol[j * BLK] = fmaxf(a, 0.0f);        // static addr: ds_write_b32
    }

    // Hidden layers: g_j = sum_k W[k][j] * h_k (row-major W matches h @ W).
    // k-loop unrolled x8 so the uniform weight loads batch and pipeline
    // ahead of the FMAs; g[] is fully statically indexed (registers).
#pragma unroll 1
    for (int l = 0; l < LCH; l++) {
        const float4* __restrict__ W4 = (const float4*)(Whid + (l << 12));
        const float*  __restrict__ bh = bhid + (l << 6);
        float g[64];
#pragma unroll
        for (int j = 0; j < 64; j++) g[j] = bh[j];
#pragma unroll 8
        for (int k = 0; k < 64; k++) {
            const float hk = hcol[k * BLK];    // ds_read_b32 (2-way alias: free)
            const float4* __restrict__ Wk = W4 + (k << 4);   // row k: 16 float4s
#pragma unroll
            for (int j4 = 0; j4 < 16; j4++) {
                float4 w = Wk[j4];             // wave-uniform (s_load) batch
                g[j4 * 4 + 0] = fmaf(w.x, hk, g[j4 * 4 + 0]);
                g[j4 * 4 + 1] = fmaf(w.y, hk, g[j4 * 4 + 1]);
                g[j4 * 4 + 2] = fmaf(w.z, hk, g[j4 * 4 + 2]);
                g[j4 * 4 + 3] = fmaf(w.w, hk, g[j4 * 4 + 3]);
            }
        }
#pragma unroll
        for (int j = 0; j < 64; j++) hcol[j * BLK] = fmaxf(g[j], 0.0f);
    }

    // Output layer collapsed over mi: vals[:,mj] = C[:,mj] + C[:,mj+2]
    float v0 = bout[0] + bout[2];
    float v1 = bout[1] + bout[3];
#pragma unroll 8
    for (int k = 0; k < 64; k++) {
        float4 wo = *((const float4*)Wout + k);
        const float hk = hcol[k * BLK];
        v0 = fmaf(hk, wo.x + wo.z, v0);
        v1 = fmaf(hk, wo.y + wo.w, v1);
    }
    if (m0 < MM) *(float2*)(vals + 2 * m0) = make_float2(v0, v1);
}

__global__ __launch_bounds__(BLK) void scatter_add(
    const float* __restrict__ vals,   // [MM,2]
    const int* __restrict__ coo,      // [2,MM]
    float* __restrict__ out)          // [DD*DD]
{
    const int t = blockIdx.x * BLK + threadIdx.x;
    if (t >= MM) return;
    const int r2 = coo[t] * 2;        // row index * MODES
    const int c2 = coo[MM + t] * 2;   // col index * MODES
    const float2 v = *(const float2*)(vals + 2 * t);
    // mj=0: element (r2, c2); mj=1: element (r2+1, c2+1) = +DD+1 flat
    const long long f0 = (long long)r2 * DD + c2;
    atomicAdd(out + f0, v.x);
    atomicAdd(out + f0 + DD + 1, v.y);
}

extern "C" void kernel_launch(void* const* d_in, const int* in_sizes, int n_in,
                              void* d_out, int out_size, void* d_ws, size_t ws_size,
                              hipStream_t stream) {
    const float* CK   = (const float*)d_in[0];
    const float* Win  = (const float*)d_in[1];
    const float* bin  = (const float*)d_in[2];
    const float* Whid = (const float*)d_in[3];
    const float* bhid = (const float*)d_in[4];
    const float* Wout = (const float*)d_in[5];
    const float* bout = (const float*)d_in[6];
    const int* coo    = (const int*)d_in[7];
    float* out        = (float*)d_out;
    float* vals       = (float*)d_ws;

    fill_mlp<<<GRID, BLK, 0, stream>>>(
        CK, Win, bin, Whid, bhid, Wout, bout, vals, out);
    scatter_add<<<(MM + BLK - 1) / BLK, BLK, 0, stream>>>(vals, coo, out);
}